// Round 12
// baseline (2008.884 us; speedup 1.0000x reference)
//
#include <hip/hip_runtime.h>

#define LROWS 8
#define MCOLS 8
#define BD 32
#define NSITE 64
#define SPB 64
#define BTOT 32768
#define NBLK (BTOT / SPB)   // 512
#define EPS 1e-10
#define PI_D 3.14159265358979323846

// ws layout (doubles):
//  W : [role4][site64][b32][a16][2] (mh,mv)     = 262144   (ROLE-MAJOR: contiguous stream per role)
//  CB: [site][role4][48] (v16 | eta2_16 | w16)  = 12288   @ 262144
//  CC: [site] c scalar                          = 64      @ 274432
#define W_OFF 0
#define CB_OFF 262144
#define CC_OFF (262144 + 12288)
#define WS_DBLS (CC_OFF + 64)

__global__ void precompute_kernel(const float* __restrict__ M_h,
                                  const float* __restrict__ M_v,
                                  const float* __restrict__ v,
                                  const float* __restrict__ w,
                                  const float* __restrict__ cc,
                                  const float* __restrict__ eta,
                                  double* __restrict__ ws) {
    int idx = blockIdx.x * 256 + threadIdx.x;
    if (idx >= WS_DBLS) return;
    double val = 0.0;
    if (idx < CB_OFF) {
        // W[r][site][b][a16][pair]
        int pair = idx & 1, a16 = (idx >> 1) & 15, b = (idx >> 5) & 31;
        int site = (idx >> 10) & 63, r = idx >> 16;
        int i = site >> 3, js = site & 7;
        int c = (i & 1) ? (MCOLS - 1 - js) : js;
        int s = r >> 1, a = (r & 1) * 16 + a16;
        if (pair == 0) val = (double)M_h[(((i * MCOLS + c) * 2 + s) * BD + a) * BD + b];
        else           val = (double)M_v[(((i * MCOLS + c) * 2 + s) * BD + a) * BD + b];
    } else if (idx < CC_OFF) {
        int j = idx - CB_OFF;
        int site = j / 192;
        int rem = j - site * 192;
        int r = rem / 48, t = rem - r * 48;
        int i = site >> 3, js = site & 7;
        int c = (i & 1) ? (MCOLS - 1 - js) : js;
        int s = r >> 1, a0 = (r & 1) * 16;
        if (t < 16)      val = (double)v[(((i * MCOLS + c) * 2 + s) * BD) + a0 + t];
        else if (t < 32) { double e = (double)eta[(i * MCOLS + c) * BD + a0 + (t - 16)]; val = e * e; }
        else             val = (double)w[(i * MCOLS + c) * BD + a0 + (t - 32)];
    } else {
        int site = idx - CC_OFF;
        int i = site >> 3, js = site & 7;
        int c = (i & 1) ? (MCOLS - 1 - js) : js;
        val = (double)cc[i * MCOLS + c];
    }
    ws[idx] = val;
}

__launch_bounds__(256, 1)
__global__ void mps_main_kernel(const int* __restrict__ x,
                                const double* __restrict__ ws,
                                float* __restrict__ out) {
    __shared__ double hRow[MCOLS][BD][SPB];   // 128 KB, lattice-column indexed
    __shared__ double pbuf[4][SPB];           // 2 KB
    __shared__ double ssb[4][SPB];            // 2 KB
    __shared__ double phb[4][SPB];            // 2 KB
    // total 134 KB -> 1 block/CU, 4 waves = 1/SIMD (minimal LDS-op pressure)

    const int tid = threadIdx.x;
    const int k = tid & 63;                  // lane = sample slot
    const int r = tid >> 6;                  // role = s*2 + a-half, wave-uniform
    const int r_u = __builtin_amdgcn_readfirstlane(r);
    const int s = r_u >> 1;
    const int abase = (r_u & 1) * 16;
    const long kg = (long)blockIdx.x * SPB + k;

    for (int t = tid; t < MCOLS * BD * SPB; t += 256) (&hRow[0][0][0])[t] = 0.0;
    __syncthreads();

    const double2* __restrict__ Wp = (const double2*)ws;  // double2 = (mh, mv)
    // role-major stream: role r's weights = Wp[r*64*512 .. (r+1)*64*512), 512 dbl2 per site,
    // chunk = 8 dbl2 (half a b-iter), 64 chunks/site, stream rolls site -> site+1 seamlessly.
    const double2* __restrict__ wstream0 = Wp + (size_t)r_u * (NSITE * 512);

    double la = 0.0, ph = 0.0;
    double2 wreg[4][8];   // 4-deep rolling chunk pipeline (slot = ch & 3, static under unroll)

    {   // preload site 0 chunks 0..3
        #pragma unroll
        for (int cch = 0; cch < 4; ++cch)
            #pragma unroll
            for (int t = 0; t < 8; ++t) wreg[cch][t] = wstream0[cch * 8 + t];
    }

    for (int i = 0; i < LROWS; ++i) {
        const int* xp = x + kg * NSITE + i * MCOLS;
        int4 xa = *reinterpret_cast<const int4*>(xp);
        int4 xb = *reinterpret_cast<const int4*>(xp + 4);
        const unsigned xbits = (unsigned)((xa.x & 1)        | ((xa.y & 1) << 1) |
                                          ((xa.z & 1) << 2) | ((xa.w & 1) << 3) |
                                          ((xb.x & 1) << 4) | ((xb.y & 1) << 5) |
                                          ((xb.z & 1) << 6) | ((xb.w & 1) << 7));
        double prodN = 1.0, prodD = 1.0;

        for (int js = 0; js < MCOLS; ++js) {
            const int site = i * MCOLS + js;
            const int c = (i & 1) ? (MCOLS - 1 - js) : js;
            const int cprev = (i & 1) ? (MCOLS - js) : (js - 1);

            // this site's chunk base in the ROLE stream (prefetch ch+4 rolls into site+1 correctly)
            const double2* __restrict__ wsite = wstream0 + (size_t)site * 512;
            const double*  __restrict__ cb    = ws + CB_OFF + (size_t)(site * 4 + r_u) * 48;

            const double* __restrict__ colV = &hRow[c][0][0];

            double acc[16];
            #pragma unroll
            for (int a = 0; a < 16; ++a) acc[a] = 0.0;

            if (js == 0) {
                #pragma unroll
                for (int b = 0; b < BD; ++b) {
                    const double hvb = colV[b * SPB + k];
                    #pragma unroll
                    for (int hf = 0; hf < 2; ++hf) {
                        const int ch = 2 * b + hf;          // 0..63, static
                        #pragma unroll
                        for (int t = 0; t < 8; ++t) {
                            const double2 w2 = wreg[ch & 3][t];
                            acc[hf * 8 + t] = fma(w2.y, hvb, acc[hf * 8 + t] + w2.x);  // h_left = 1
                        }
                        // refill consumed slot with chunk ch+4 of the role stream
                        const double2* __restrict__ wn = wsite + (ch + 4) * 8;
                        #pragma unroll
                        for (int t = 0; t < 8; ++t) wreg[ch & 3][t] = wn[t];
                    }
                }
            } else {
                const double* __restrict__ colL = &hRow[cprev][0][0];
                #pragma unroll
                for (int b = 0; b < BD; ++b) {
                    const double hlb = colL[b * SPB + k];
                    const double hvb = colV[b * SPB + k];
                    #pragma unroll
                    for (int hf = 0; hf < 2; ++hf) {
                        const int ch = 2 * b + hf;
                        #pragma unroll
                        for (int t = 0; t < 8; ++t) {
                            const double2 w2 = wreg[ch & 3][t];
                            acc[hf * 8 + t] = fma(w2.x, hlb, fma(w2.y, hvb, acc[hf * 8 + t]));
                        }
                        const double2* __restrict__ wn = wsite + (ch + 4) * 8;
                        #pragma unroll
                        for (int t = 0; t < 8; ++t) wreg[ch & 3][t] = wn[t];
                    }
                }
            }
            #pragma unroll
            for (int a = 0; a < 16; ++a) acc[a] += cb[a];   // v bias (late add)

            // partials over this role's 16 accs
            double pp = 0.0, ssp = 0.0, php = 0.0;
            #pragma unroll
            for (int a = 0; a < 16; ++a) {
                const double t2 = acc[a] * acc[a];
                pp  = fma(t2, cb[16 + a], pp);
                ssp += t2;
                php = fma(acc[a], cb[32 + a], php);
            }
            const double ccoef = ws[CC_OFF + site];
            const int xs = (int)((xbits >> js) & 1u);
            const bool sel = (s == xs);

            pbuf[r][k] = pp;
            ssb[r][k]  = ssp;
            phb[r][k]  = php;
            __syncthreads();   // bar1: partials visible

            const int gb = xs * 2;   // selected role group (2 roles)
            const double ss = ssb[gb][k] + ssb[gb + 1][k];
            const double inv = 1.0 / (sqrt(ss) + EPS);
            if (sel) {
                #pragma unroll
                for (int a = 0; a < 16; ++a)
                    hRow[c][abase + a][k] = acc[a] * inv;   // h_left next site / h_below next row
            }

            if (r_u == 0) {   // only wave 0 carries la/ph
                const double p0 = pbuf[0][k] + pbuf[1][k];
                const double p1 = pbuf[2][k] + pbuf[3][k];
                const double psel = xs ? p1 : p0;
                prodN *= (psel + EPS);
                prodD *= (p0 + p1 + EPS);
                const double phd = phb[gb][k] + phb[gb + 1][k];
                const double aph = phd * inv + ccoef;
                ph += (aph < 0.0) ? PI_D : 0.0;
            }

            __syncthreads();   // bar2: hRow updated
        }
        if (r_u == 0) la += 0.5 * (log(prodN) - log(prodD));
    }

    if (r == 0) {
        out[kg * 2]     = (float)la;
        out[kg * 2 + 1] = (float)ph;
    }
}

extern "C" void kernel_launch(void* const* d_in, const int* in_sizes, int n_in,
                              void* d_out, int out_size, void* d_ws, size_t ws_size,
                              hipStream_t stream) {
    const int*   x    = (const int*)d_in[0];
    const float* M_h  = (const float*)d_in[1];
    const float* M_v  = (const float*)d_in[2];
    const float* v    = (const float*)d_in[3];
    const float* w    = (const float*)d_in[4];
    const float* cc   = (const float*)d_in[5];
    const float* eta  = (const float*)d_in[6];
    float* out = (float*)d_out;
    double* ws = (double*)d_ws;

    const int pre_total = WS_DBLS;
    dim3 preGrid((pre_total + 255) / 256), preBlock(256);
    hipLaunchKernelGGL(precompute_kernel, preGrid, preBlock, 0, stream,
                       M_h, M_v, v, w, cc, eta, ws);

    dim3 grid(NBLK), block(256);
    hipLaunchKernelGGL(mps_main_kernel, grid, block, 0, stream, x, ws, out);
}

// Round 13
// 654.482 us; speedup vs baseline: 3.0694x; 3.0694x over previous
//
#include <hip/hip_runtime.h>

#define LROWS 8
#define MCOLS 8
#define BD 32
#define NSITE 64
#define SPB 64
#define BTOT 32768
#define NBLK (BTOT / SPB)   // 512
#define EPS 1e-10
#define PI_D 3.14159265358979323846

// ws layout (doubles) — identical to round 10:
//  W : [site][role16][b32][a4][2] (mh,mv pairs) = 262144
//  CB: [site][role16][12] (v4 | eta2_4 | w4)    = 12288   @ 262144
//  CC: [site] c scalar                          = 64      @ 274432
#define W_OFF 0
#define CB_OFF 262144
#define CC_OFF (262144 + 12288)
#define WS_DBLS (CC_OFF + 64)

__global__ void precompute_kernel(const float* __restrict__ M_h,
                                  const float* __restrict__ M_v,
                                  const float* __restrict__ v,
                                  const float* __restrict__ w,
                                  const float* __restrict__ cc,
                                  const float* __restrict__ eta,
                                  double* __restrict__ ws) {
    int idx = blockIdx.x * 256 + threadIdx.x;
    if (idx >= WS_DBLS) return;
    double val = 0.0;
    if (idx < CB_OFF) {
        int pair = idx & 1, a4 = (idx >> 1) & 3, b = (idx >> 3) & 31;
        int r = (idx >> 8) & 15, site = idx >> 12;
        int i = site >> 3, js = site & 7;
        int c = (i & 1) ? (MCOLS - 1 - js) : js;
        int s = r >> 3, a = (r & 7) * 4 + a4;
        if (pair == 0) val = (double)M_h[(((i * MCOLS + c) * 2 + s) * BD + a) * BD + b];
        else           val = (double)M_v[(((i * MCOLS + c) * 2 + s) * BD + a) * BD + b];
    } else if (idx < CC_OFF) {
        int j = idx - CB_OFF;
        int site = j / 192;
        int rem = j - site * 192;
        int r = rem / 12, t = rem - r * 12;
        int i = site >> 3, js = site & 7;
        int c = (i & 1) ? (MCOLS - 1 - js) : js;
        int s = r >> 3, a0 = (r & 7) * 4;
        if (t < 4)      val = (double)v[(((i * MCOLS + c) * 2 + s) * BD) + a0 + t];
        else if (t < 8) { double e = (double)eta[(i * MCOLS + c) * BD + a0 + (t - 4)]; val = e * e; }
        else            val = (double)w[(i * MCOLS + c) * BD + a0 + (t - 8)];
    } else {
        int site = idx - CC_OFF;
        int i = site >> 3, js = site & 7;
        int c = (i & 1) ? (MCOLS - 1 - js) : js;
        val = (double)cc[i * MCOLS + c];
    }
    ws[idx] = val;
}

__launch_bounds__(1024, 1)
__global__ void mps_main_kernel(const int* __restrict__ x,
                                const double* __restrict__ ws,
                                float* __restrict__ out) {
    __shared__ double hRow[MCOLS][BD][SPB];   // 128 KB, lattice-column indexed
    __shared__ float  pbuf[2][16][SPB];       // 8 KB  (parity dbuf; feeds la only -> fp32 ok)
    __shared__ double ssb[16 >> 1][SPB];      // 4 KB  (complementary-mask slot r&7, in-window)
    __shared__ double phb[2][8][SPB];         // 8 KB  (parity dbuf, complementary-mask slot r&7)
    // total 148 KB -> 1 block/CU, 16 waves = 4/SIMD

    const int tid = threadIdx.x;
    const int k = tid & 63;                  // lane = sample slot
    const int r = tid >> 6;                  // role = s*8 + a-quartet, wave-uniform
    const int r_u = __builtin_amdgcn_readfirstlane(r);
    const int s = r_u >> 3;
    const int abase = (r_u & 7) * 4;
    const int j8 = r_u & 7;                  // complementary slot (s=0 and s=1 waves share)
    const long kg = (long)blockIdx.x * SPB + k;

    for (int t = tid; t < MCOLS * BD * SPB; t += 1024) (&hRow[0][0][0])[t] = 0.0;
    __syncthreads();

    const double2* __restrict__ Wp = (const double2*)ws;  // double2 = (mh, mv)

    double la = 0.0, ph = 0.0;
    double prodN = 1.0, prodD = 1.0;
    int par = 0;
    double2 wreg[2][8];   // double-buffered uniform weight prefetch (2 b-iters deep)

    {   // preload site 0, block 0
        const double2* __restrict__ w0 = Wp + (size_t)r_u * 128;
        #pragma unroll
        for (int t = 0; t < 8; ++t) wreg[0][t] = w0[t];
    }

    for (int i = 0; i < LROWS; ++i) {
        const int* xp = x + kg * NSITE + i * MCOLS;
        int4 xa = *reinterpret_cast<const int4*>(xp);
        int4 xb = *reinterpret_cast<const int4*>(xp + 4);
        const unsigned xbits = (unsigned)((xa.x & 1)        | ((xa.y & 1) << 1) |
                                          ((xa.z & 1) << 2) | ((xa.w & 1) << 3) |
                                          ((xb.x & 1) << 4) | ((xb.y & 1) << 5) |
                                          ((xb.z & 1) << 6) | ((xb.w & 1) << 7));
        prodN = 1.0; prodD = 1.0;

        for (int js = 0; js < MCOLS; ++js) {
            const int site = i * MCOLS + js;
            const int c = (i & 1) ? (MCOLS - 1 - js) : js;
            const int cprev = (i & 1) ? (MCOLS - js) : (js - 1);

            const double2* __restrict__ wsite = Wp + (size_t)(site * 16 + r_u) * 128;
            const double*  __restrict__ cb    = ws + CB_OFF + (size_t)(site * 16 + r_u) * 12;

            const double* __restrict__ colV = &hRow[c][0][0];

            double acc[4];
            #pragma unroll
            for (int a = 0; a < 4; ++a) acc[a] = 0.0;

            // ---- software-pipelined matvec: 16 blocks of 2 b-iters ----
            if (js == 0) {
                #pragma unroll
                for (int bb = 0; bb < 16; ++bb) {
                    const int cur = bb & 1;
                    if (bb < 15) {
                        const double2* __restrict__ wn = wsite + (bb + 1) * 8;
                        #pragma unroll
                        for (int t = 0; t < 8; ++t) wreg[cur ^ 1][t] = wn[t];
                    }
                    #pragma unroll
                    for (int bq = 0; bq < 2; ++bq) {
                        const int b = bb * 2 + bq;
                        const double hvb = colV[b * SPB + k];
                        #pragma unroll
                        for (int a = 0; a < 4; ++a) {
                            const double2 w2 = wreg[cur][bq * 4 + a];
                            acc[a] = fma(w2.y, hvb, acc[a] + w2.x);   // h_left = 1
                        }
                    }
                }
            } else {
                const double* __restrict__ colL = &hRow[cprev][0][0];
                #pragma unroll
                for (int bb = 0; bb < 16; ++bb) {
                    const int cur = bb & 1;
                    if (bb < 15) {
                        const double2* __restrict__ wn = wsite + (bb + 1) * 8;
                        #pragma unroll
                        for (int t = 0; t < 8; ++t) wreg[cur ^ 1][t] = wn[t];
                    }
                    #pragma unroll
                    for (int bq = 0; bq < 2; ++bq) {
                        const int b = bb * 2 + bq;
                        const double hlb = colL[b * SPB + k];
                        const double hvb = colV[b * SPB + k];
                        #pragma unroll
                        for (int a = 0; a < 4; ++a) {
                            const double2 w2 = wreg[cur][bq * 4 + a];
                            acc[a] = fma(w2.x, hlb, fma(w2.y, hvb, acc[a]));
                        }
                    }
                }
            }
            #pragma unroll
            for (int a = 0; a < 4; ++a) acc[a] += cb[a];   // v bias (late add)

            // partials over this role's 4 accs
            double pp = 0.0, ssp = 0.0, php = 0.0;
            #pragma unroll
            for (int a = 0; a < 4; ++a) {
                const double t2 = acc[a] * acc[a];
                pp  = fma(t2, cb[4 + a], pp);
                ssp += t2;
                php = fma(acc[a], cb[8 + a], php);
            }
            const double ccoef = ws[CC_OFF + site];
            const int xs = (int)((xbits >> js) & 1u);
            const bool sel = (s == xs);

            pbuf[par][r][k] = (float)pp;
            if (sel) { ssb[j8][k] = ssp; phb[par][j8][k] = php; }  // complementary lane masks
            __syncthreads();   // bar1: partials visible

            // prefetch NEXT site's block 0 (drained by bar2 = covered by window)
            {
                const double2* __restrict__ wn = Wp + (size_t)((site + 1) * 16 + r_u) * 128;
                #pragma unroll
                for (int t = 0; t < 8; ++t) wreg[0][t] = wn[t];
            }

            // ---- minimal window: ss reduce + inv + hRow write only ----
            const double ss = (((ssb[0][k] + ssb[1][k]) + (ssb[2][k] + ssb[3][k]))
                             + ((ssb[4][k] + ssb[5][k]) + (ssb[6][k] + ssb[7][k])));
            const double inv = 1.0 / (sqrt(ss) + EPS);
            if (sel) {
                #pragma unroll
                for (int a = 0; a < 4; ++a)
                    hRow[c][abase + a][k] = acc[a] * inv;   // h_left next site / h_below next row
            }
            __syncthreads();   // bar2: hRow updated

            // ---- epilogue (wave 0 only): overlaps other waves' next matvec ----
            if (r_u == 0) {
                const float* __restrict__ pb = &pbuf[par][0][0];
                const double p0 = (double)((((pb[0*SPB+k] + pb[1*SPB+k]) + (pb[2*SPB+k] + pb[3*SPB+k]))
                                          + ((pb[4*SPB+k] + pb[5*SPB+k]) + (pb[6*SPB+k] + pb[7*SPB+k]))));
                const double p1 = (double)((((pb[8*SPB+k] + pb[9*SPB+k]) + (pb[10*SPB+k] + pb[11*SPB+k]))
                                          + ((pb[12*SPB+k] + pb[13*SPB+k]) + (pb[14*SPB+k] + pb[15*SPB+k]))));
                const double psel = xs ? p1 : p0;
                prodN *= (psel + EPS);
                prodD *= (p0 + p1 + EPS);
                const double phd = (((phb[par][0][k] + phb[par][1][k]) + (phb[par][2][k] + phb[par][3][k]))
                                  + ((phb[par][4][k] + phb[par][5][k]) + (phb[par][6][k] + phb[par][7][k])));
                const double aph = phd * inv + ccoef;
                ph += (aph < 0.0) ? PI_D : 0.0;
            }
            par ^= 1;
        }
        if (r_u == 0) la += 0.5 * (log(prodN) - log(prodD));
    }

    if (r == 0) {
        out[kg * 2]     = (float)la;
        out[kg * 2 + 1] = (float)ph;
    }
}

extern "C" void kernel_launch(void* const* d_in, const int* in_sizes, int n_in,
                              void* d_out, int out_size, void* d_ws, size_t ws_size,
                              hipStream_t stream) {
    const int*   x    = (const int*)d_in[0];
    const float* M_h  = (const float*)d_in[1];
    const float* M_v  = (const float*)d_in[2];
    const float* v    = (const float*)d_in[3];
    const float* w    = (const float*)d_in[4];
    const float* cc   = (const float*)d_in[5];
    const float* eta  = (const float*)d_in[6];
    float* out = (float*)d_out;
    double* ws = (double*)d_ws;

    const int pre_total = WS_DBLS;
    dim3 preGrid((pre_total + 255) / 256), preBlock(256);
    hipLaunchKernelGGL(precompute_kernel, preGrid, preBlock, 0, stream,
                       M_h, M_v, v, w, cc, eta, ws);

    dim3 grid(NBLK), block(1024);
    hipLaunchKernelGGL(mps_main_kernel, grid, block, 0, stream, x, ws, out);
}